// Round 11
// baseline (546.248 us; speedup 1.0000x reference)
//
#include <hip/hip_runtime.h>
#include <hip/hip_bf16.h>
#include <math.h>

#define N_PTS  100000
#define M_CL   2048
#define E_EDG  65536
#define IN_DIM 512
#define HID    256
// TAU = 0.5 -> 1/TAU = 2.0 ; LAMDA = 1.0 (folded)

typedef unsigned short u16;
typedef __attribute__((ext_vector_type(8))) short bf16x8;
typedef __attribute__((ext_vector_type(4))) float f32x4;

__device__ __forceinline__ u16 f2bf(float f){
  __hip_bfloat16 h = __float2bfloat16(f);
  return *reinterpret_cast<u16*>(&h);
}
__device__ __forceinline__ unsigned pk2(float a, float b){
  return (unsigned)f2bf(a) | ((unsigned)f2bf(b) << 16);
}
__device__ __forceinline__ float bf2f(u16 v){
  return __uint_as_float((unsigned)v << 16);
}
// async global->LDS, 16B per lane: HW dest = wave-uniform base + lane*16B.
__device__ __forceinline__ void glds16(const u16* g, u16* lds_base_uniform){
  __builtin_amdgcn_global_load_lds(
      (const __attribute__((address_space(1))) unsigned int*)(g),
      (__attribute__((address_space(3))) unsigned int*)(lds_base_uniform), 16, 0, 0);
}
#define VMWAIT0() do{ asm volatile("s_waitcnt vmcnt(0)" ::: "memory"); __builtin_amdgcn_sched_barrier(0);}while(0)
#define VMWAIT8() do{ asm volatile("s_waitcnt vmcnt(8)" ::: "memory"); __builtin_amdgcn_sched_barrier(0);}while(0)

// ---------------- workspace layout (bytes) ----------------
// FIXED r9/r10 bug: start_e needs (M+1)*4 = 8196 B; sortpt moved 66560 -> 66816
// so start_e[2048] no longer aliases sortpt[0].
static const size_t OFF_POSACC = 0;              // M floats
static const size_t OFF_NEGSUM = 8192;           // M floats
static const size_t OFF_CURP   = 16384;          // M ints
static const size_t OFF_CURE   = 24576;          // M ints
static const size_t OFF_HISTP  = 32768;          // M ints
static const size_t OFF_HISTE  = 40960;          // M ints
static const size_t OFF_LOSS   = 49152;          // 1 double
static const size_t OFF_DONE   = 49160;          // 1 int
static const int    ZERO_U32   = 12291;          // 49164 / 4
static const size_t OFF_STARTP = 49664;          // M+1 ints (ends 57860)
static const size_t OFF_STARTE = 58368;          // M+1 ints (ends 66564)
static const size_t OFF_SORTPT = 66816;          // N ints   (ends 466816)
static const size_t OFF_SCOL   = 466944;         // E ints   (ends 729088)
static const size_t OFF_SVAL   = 729088;         // E floats (ends 991232)
static const size_t OFF_CNT    = 991232;         // M floats
static const size_t OFF_XC     = 999424;         // M*512 f32
static const size_t OFF_Q      = 5193728;        // M*256 f32
static const size_t OFF_HNB    = 7290880;        // M*256 u16
static const size_t OFF_NEGB   = 8388608;        // M*M u16 = 8 MB
static const size_t OFF_WT0T   = 16777216;       // 256*512 bf16
static const size_t OFF_WT1T   = 17039360;       // 256*256 bf16
static const size_t OFF_XBF    = 33554432;       // N*512 bf16 = 102.4 MB
static const size_t OFF_TBUF   = 150994944;      // 100096*256 bf16 = 51.25 MB
static const size_t OFF_PSS    = 260046848;      // N*2 floats
static const size_t OFF_PD     = 268435456;      // N*2 floats

// ---------------- k_pre0: zero the accumulator/hist region ----------------
__global__ __launch_bounds__(256) void k_pre0(unsigned* __restrict__ p){
  int i = blockIdx.x*256 + threadIdx.x;
  if (i < ZERO_U32) p[i] = 0u;
}

// ---------------- k_hist: both histograms, block-range branched ----------------
#define NB_HP ((N_PTS + 255)/256)   // 391
#define NB_HE ((E_EDG + 255)/256)   // 256
__global__ __launch_bounds__(256) void k_hist(const int* __restrict__ pas, const int* __restrict__ cgr,
                                              int* __restrict__ hist_p, int* __restrict__ hist_e){
  const int b = blockIdx.x, t = threadIdx.x;
  if (b < NB_HP){
    int i = b*256 + t;
    if (i < N_PTS) atomicAdd(&hist_p[pas[i]], 1);
  } else {
    int e = (b - NB_HP)*256 + t;
    if (e < E_EDG) atomicAdd(&hist_e[cgr[e]], 1);
  }
}

// ---------------- k_scan2: exclusive scans of both histograms (1 block) ----------------
__device__ __forceinline__ void scan8(const int* __restrict__ hist, int* __restrict__ start, int* part){
  const int t = threadIdx.x;
  int v[8]; int s = 0;
#pragma unroll
  for (int j=0;j<8;j++){ v[j] = hist[t*8+j]; s += v[j]; }
  part[t] = s;
  __syncthreads();
  if (t == 0){
    int run = 0;
    for (int i=0;i<256;i++){ int tmp = part[i]; part[i] = run; run += tmp; }
  }
  __syncthreads();
  int run = part[t];
#pragma unroll
  for (int j=0;j<8;j++){ start[t*8+j] = run; run += v[j]; }
  if (t == 255) start[M_CL] = run;
}
__global__ __launch_bounds__(256) void k_scan2(const int* __restrict__ hp, int* __restrict__ sp,
                                               const int* __restrict__ he, int* __restrict__ se){
  __shared__ int part[256];
  scan8(hp, sp, part);
  __syncthreads();
  scan8(he, se, part);
}

// ---------------- k_misc: scatters + weight transposes ----------------
#define NB_P  ((N_PTS + 255)/256)
#define NB_E  ((E_EDG + 255)/256)
#define NB_T0 ((256*512)/256)
#define NB_T1 ((256*256)/256)
__global__ __launch_bounds__(256) void k_misc(
    const int* __restrict__ pas, const int* __restrict__ cgr, const int* __restrict__ cgc,
    const float* __restrict__ cgv, const int* __restrict__ start_p, const int* __restrict__ start_e,
    int* __restrict__ cur_p, int* __restrict__ cur_e,
    int* __restrict__ sortpt, int* __restrict__ scol, float* __restrict__ sval,
    const float* __restrict__ Wt0, const float* __restrict__ Wt1,
    u16* __restrict__ Wt0t, u16* __restrict__ Wt1t){
  const int b = blockIdx.x, t = threadIdx.x;
  if (b < NB_P){
    int i = b*256 + t;
    if (i < N_PTS){
      int r = pas[i];
      int p = start_p[r] + atomicAdd(&cur_p[r], 1);
      sortpt[p] = i;
    }
  } else if (b < NB_P + NB_E){
    int e = (b - NB_P)*256 + t;
    if (e < E_EDG){
      int r = cgr[e];
      int p = start_e[r] + atomicAdd(&cur_e[r], 1);
      scol[p] = cgc[e];
      sval[p] = cgv[e];
    }
  } else if (b < NB_P + NB_E + NB_T0){
    int o = (b - NB_P - NB_E)*256 + t;
    int n = o / IN_DIM, k = o % IN_DIM;
    Wt0t[o] = f2bf(Wt0[(size_t)k*HID + n]);
  } else {
    int o = (b - NB_P - NB_E - NB_T0)*256 + t;
    int n = o / HID, k = o % HID;
    Wt1t[o] = f2bf(Wt1[(size_t)k*HID + n]);
  }
}

// ---------------- Xc = segsum(p*x), cnt = segsum(p), xbf = bf16(x) ----------------
__global__ __launch_bounds__(256) void k_cluster_agg(const float* __restrict__ x, const float* __restrict__ pv,
                                                     const int* __restrict__ sorted_pt, const int* __restrict__ start,
                                                     float* __restrict__ Xc, float* __restrict__ cnt,
                                                     u16* __restrict__ xbf){
  const int m = blockIdx.x;
  const int t = threadIdx.x;
  const int half = t >> 7;
  const int u = t & 127;
  const int s0 = start[m], s1 = start[m+1];
  f32x4 a = {0.f,0.f,0.f,0.f};
  float c = 0.f;
  for (int p = s0 + half; p < s1; p += 2){
    int row = sorted_pt[p];
    float w = pv[row];
    f32x4 xv = *reinterpret_cast<const f32x4*>(x + (size_t)row*IN_DIM + u*4);
    a.x = fmaf(w, xv.x, a.x); a.y = fmaf(w, xv.y, a.y);
    a.z = fmaf(w, xv.z, a.z); a.w = fmaf(w, xv.w, a.w);
    c += w;
    uint2 pk; pk.x = pk2(xv.x, xv.y); pk.y = pk2(xv.z, xv.w);
    *reinterpret_cast<uint2*>(xbf + (size_t)row*IN_DIM + u*4) = pk;
  }
  __shared__ __align__(16) float sh[128*4];
  __shared__ float shc[2];
  if (half == 1) *reinterpret_cast<f32x4*>(sh + u*4) = a;
  if (t == 0)   shc[0] = c;
  if (t == 128) shc[1] = c;
  __syncthreads();
  if (half == 0){
    f32x4 b = *reinterpret_cast<const f32x4*>(sh + u*4);
    a.x += b.x; a.y += b.y; a.z += b.z; a.w += b.w;
    *reinterpret_cast<f32x4*>(Xc + (size_t)m*IN_DIM + u*4) = a;
    if (t == 0) cnt[m] = shc[0] + shc[1];
  }
}

// ---------------- fused M-scale chain ----------------
template<int K>
__device__ __forceinline__ void mc_layer(const float* __restrict__ W, const float* act, int t, float acc[4]){
#pragma unroll
  for (int r=0;r<4;r++) acc[r] = 0.f;
#pragma unroll 2
  for (int k=0;k<K;k+=4){
    float w0 = W[(size_t)(k+0)*HID + t];
    float w1 = W[(size_t)(k+1)*HID + t];
    float w2 = W[(size_t)(k+2)*HID + t];
    float w3 = W[(size_t)(k+3)*HID + t];
#pragma unroll
    for (int r=0;r<4;r++){
      float4 av = *reinterpret_cast<const float4*>(act + r*K + k);
      acc[r] = fmaf(av.x, w0, acc[r]);
      acc[r] = fmaf(av.y, w1, acc[r]);
      acc[r] = fmaf(av.z, w2, acc[r]);
      acc[r] = fmaf(av.w, w3, acc[r]);
    }
  }
}

__global__ __launch_bounds__(256) void k_mchain(
    const float* __restrict__ Xc, const float* __restrict__ cnt,
    const float* __restrict__ We0, const float* __restrict__ be0,
    const float* __restrict__ We1, const float* __restrict__ be1,
    const float* __restrict__ Wp0, const float* __restrict__ bp0,
    const float* __restrict__ Wp1, const float* __restrict__ bp1,
    u16* __restrict__ hnb, float* __restrict__ q){
  __shared__ __align__(16) float a_sh[4*512];
  __shared__ __align__(16) float b_sh[4*256];
  __shared__ float part[4][4];
  const int t = threadIdx.x;
  const int rb = blockIdx.x*4;
  for (int i=t; i<4*128; i+=256){
    int r = i>>7, k4 = i&127;
    reinterpret_cast<float4*>(a_sh + r*512)[k4] =
      reinterpret_cast<const float4*>(Xc + (size_t)(rb+r)*IN_DIM)[k4];
  }
  float cv[4];
#pragma unroll
  for (int r=0;r<4;r++) cv[r] = cnt[rb+r];
  __syncthreads();

  float acc[4], v[4];
  mc_layer<512>(We0, a_sh, t, acc);
  {
    float b = be0[t];
#pragma unroll
    for (int r=0;r<4;r++) b_sh[r*256+t] = fmaf(cv[r], b, acc[r]);
  }
  __syncthreads();
  mc_layer<256>(We1, b_sh, t, acc);
  {
    float b = be1[t];
#pragma unroll
    for (int r=0;r<4;r++){
      v[r] = fmaf(cv[r], b, acc[r]);
      float s = v[r]*v[r];
#pragma unroll
      for (int off=32;off;off>>=1) s += __shfl_xor(s, off, 64);
      if ((t&63) == 0) part[t>>6][r] = s;
      a_sh[r*256+t] = v[r];
    }
  }
  __syncthreads();
#pragma unroll
  for (int r=0;r<4;r++){
    float tot = part[0][r]+part[1][r]+part[2][r]+part[3][r];
    float inv = 1.0f / fmaxf(sqrtf(tot), 1e-12f);
    hnb[(size_t)(rb+r)*HID + t] = f2bf(v[r]*inv);
  }
  mc_layer<256>(Wp0, a_sh, t, acc);
  {
    float b = bp0[t];
#pragma unroll
    for (int r=0;r<4;r++) b_sh[r*256+t] = fmaxf(acc[r]+b, 0.f);
  }
  __syncthreads();
  mc_layer<256>(Wp1, b_sh, t, acc);
  {
    float b = bp1[t];
#pragma unroll
    for (int r=0;r<4;r++){
      v[r] = acc[r] + b;
      float s = v[r]*v[r];
#pragma unroll
      for (int off=32;off;off>>=1) s += __shfl_xor(s, off, 64);
      if ((t&63) == 0) part[t>>6][r] = s;
    }
  }
  __syncthreads();
#pragma unroll
  for (int r=0;r<4;r++){
    float tot = part[0][r]+part[1][r]+part[2][r]+part[3][r];
    float inv = 1.0f / fmaxf(sqrtf(tot), 1e-12f);
    q[(size_t)(rb+r)*HID + t] = v[r]*inv;
  }
}

// ---------------- k_t0: T = X @ Wt0 + bt0, persistent 64-row weight quarter in LDS ----------------
// 256 blocks (1/CU), 512 thr (8 waves). Block b: n-quarter = b&3, pair = b>>2 (0..63).
// LDS: [16 ks][64 n][32 u16] = 64 KB static. 4 co-walking quarters -> x L2-hits.
#define NT0_TILES ((N_PTS + 255)/256)   // 391
__global__ __launch_bounds__(512,2) void k_t0(
    const u16* __restrict__ xbf, const u16* __restrict__ Wt0t, const float* __restrict__ bt0,
    u16* __restrict__ tbuf){
  __shared__ u16 wbuf[16*64*32];    // 64 KB
  const int t  = threadIdx.x;
  const int w  = t >> 6;            // 0..7
  const int l  = t & 63;
  const int c  = l & 15;
  const int lg = l >> 4;
  const int nq   = blockIdx.x & 3;
  const int pair = blockIdx.x >> 2; // 0..63
  const int nbase = nq*64;

  // ---- prologue: stage 64x512 quarter-panel. Wave w stages ks {2w, 2w+1}. ----
  {
#pragma unroll
    for (int kk=0; kk<2; kk++){
      const int ks = 2*w + kk;
#pragma unroll
      for (int i_=0; i_<4; i_++){
        int row = i_*16 + (l>>2);
        int ug  = (l&3) ^ ((row>>1)&3);
        glds16(Wt0t + (size_t)(nbase + row)*IN_DIM + ks*32 + ug*8,
               wbuf + ks*2048 + i_*512);
      }
    }
  }
  VMWAIT0();
  __syncthreads();

  const int su = lg ^ ((c>>1)&3);

  for (int tile = pair; tile < NT0_TILES; tile += 64){
    const int m0 = tile*256 + w*32;
    int g0 = m0 + c;      if (g0 > N_PTS-1) g0 = N_PTS-1;
    int g1 = m0 + 16 + c; if (g1 > N_PTS-1) g1 = N_PTS-1;
    const u16* xr0 = xbf + (size_t)g0*IN_DIM + lg*8;
    const u16* xr1 = xbf + (size_t)g1*IN_DIM + lg*8;

    f32x4 acc[2][4];
#pragma unroll
    for (int i=0;i<2;i++)
#pragma unroll
      for (int j=0;j<4;j++){ acc[i][j].x=0.f; acc[i][j].y=0.f; acc[i][j].z=0.f; acc[i][j].w=0.f; }

    bf16x8 xa = *reinterpret_cast<const bf16x8*>(xr0);
    bf16x8 xb = *reinterpret_cast<const bf16x8*>(xr1);
#pragma unroll
    for (int ks=0; ks<16; ks++){
      bf16x8 cxa = xa, cxb = xb;
      if (ks < 15){
        xa = *reinterpret_cast<const bf16x8*>(xr0 + (ks+1)*32);
        xb = *reinterpret_cast<const bf16x8*>(xr1 + (ks+1)*32);
      }
#pragma unroll
      for (int nf=0; nf<4; nf++){
        bf16x8 afr = *reinterpret_cast<const bf16x8*>(wbuf + ks*2048 + (nf*16+c)*32 + su*8);
        acc[0][nf] = __builtin_amdgcn_mfma_f32_16x16x32_bf16(afr, cxa, acc[0][nf], 0,0,0);
        acc[1][nf] = __builtin_amdgcn_mfma_f32_16x16x32_bf16(afr, cxb, acc[1][nf], 0,0,0);
      }
    }

    // epilogue: + bt0, pack bf16, store T[m][nbase + nf*16 + lg*4 .. +3]
#pragma unroll
    for (int nf=0; nf<4; nf++){
      f32x4 b = *reinterpret_cast<const f32x4*>(bt0 + nbase + nf*16 + lg*4);
#pragma unroll
      for (int mf=0; mf<2; mf++){
        int m = m0 + mf*16 + c;
        f32x4 v = acc[mf][nf] + b;
        uint2 p; p.x = pk2(v.x, v.y); p.y = pk2(v.z, v.w);
        *reinterpret_cast<uint2*>(tbuf + (size_t)m*HID + nbase + nf*16 + lg*4) = p;
      }
    }
  }
}

// ---------------- k_t1: partial V = T @ Wt1 + bt1 over an n-half; partial ss/d out ----------------
// 256 blocks (1/CU), 512 thr (8 waves). Block b: half = b&1, pair = b>>1 (0..127).
// LDS: [8 ks][128 n][32 u16] = 64 KB static. Wave w stages ks = w.
#define NT1_TILES ((N_PTS + 127)/128)   // 782
__global__ __launch_bounds__(512,2) void k_t1(
    const u16* __restrict__ tbuf, const u16* __restrict__ Wt1t, const float* __restrict__ bt1,
    const float* __restrict__ q, const int* __restrict__ assign,
    float* __restrict__ pss, float* __restrict__ pd){
  __shared__ u16 wbuf[8*128*32];    // 64 KB
  const int t  = threadIdx.x;
  const int w  = t >> 6;            // 0..7
  const int l  = t & 63;
  const int c  = l & 15;
  const int lg = l >> 4;
  const int half = blockIdx.x & 1;
  const int pair = blockIdx.x >> 1; // 0..127
  const int nbase = half*128;

  // ---- prologue: stage 128x256 half-panel; wave w stages ks = w (8 glds) ----
  {
    const int ks = w;
#pragma unroll
    for (int i_=0; i_<8; i_++){
      int row = i_*16 + (l>>2);
      int ug  = (l&3) ^ ((row>>1)&3);
      glds16(Wt1t + (size_t)(nbase + row)*HID + ks*32 + ug*8,
             wbuf + ks*4096 + i_*512);
    }
  }
  VMWAIT0();
  __syncthreads();

  const int su = lg ^ ((c>>1)&3);

  for (int tile = pair; tile < NT1_TILES; tile += 128){
    const int gm = tile*128 + w*16 + c;
    const int gmc = (gm < N_PTS) ? gm : (N_PTS-1);
    const u16* trow = tbuf + (size_t)gmc*HID + lg*8;

    f32x4 acc[8];
#pragma unroll
    for (int j=0;j<8;j++){ acc[j].x=0.f; acc[j].y=0.f; acc[j].z=0.f; acc[j].w=0.f; }

    bf16x8 xa = *reinterpret_cast<const bf16x8*>(trow);
#pragma unroll
    for (int ks=0; ks<8; ks++){
      bf16x8 cxa = xa;
      if (ks < 7) xa = *reinterpret_cast<const bf16x8*>(trow + (ks+1)*32);
#pragma unroll
      for (int nf=0; nf<8; nf++){
        bf16x8 afr = *reinterpret_cast<const bf16x8*>(wbuf + ks*4096 + (nf*16+c)*32 + su*8);
        acc[nf] = __builtin_amdgcn_mfma_f32_16x16x32_bf16(afr, cxa, acc[nf], 0,0,0);
      }
    }

    // partial epilogue: +bt1, partial ||v||^2 and v.q over this n-half
    const int cl = assign[gmc];
    const float* qrow = q + (size_t)cl*HID + nbase + lg*4;
    float ss = 0.f, d = 0.f;
#pragma unroll
    for (int nf=0; nf<8; nf++){
      f32x4 b  = *reinterpret_cast<const f32x4*>(bt1 + nbase + nf*16 + lg*4);
      f32x4 qv = *reinterpret_cast<const f32x4*>(qrow + nf*16);
      f32x4 v  = acc[nf] + b;
      ss = fmaf(v.x,v.x, fmaf(v.y,v.y, fmaf(v.z,v.z, fmaf(v.w,v.w, ss))));
      d  = fmaf(v.x,qv.x, fmaf(v.y,qv.y, fmaf(v.z,qv.z, fmaf(v.w,qv.w, d))));
    }
    ss += __shfl_xor(ss, 16, 64); ss += __shfl_xor(ss, 32, 64);
    d  += __shfl_xor(d , 16, 64); d  += __shfl_xor(d , 32, 64);
    if (lg == 0 && gm < N_PTS){
      pss[(size_t)gm*2 + half] = ss;
      pd [(size_t)gm*2 + half] = d;
    }
  }
}

// ---------------- k_t2: combine halves -> posacc ----------------
__global__ __launch_bounds__(256) void k_t2(const float* __restrict__ pss, const float* __restrict__ pd,
                                            const int* __restrict__ assign, const float* __restrict__ pv,
                                            float* __restrict__ posacc){
  int i = blockIdx.x*256 + threadIdx.x;
  if (i < N_PTS){
    float ss = pss[2*i] + pss[2*i+1];
    float d  = pd[2*i]  + pd[2*i+1];
    float inv = 1.0f / fmaxf(sqrtf(ss), 1e-12f);
    atomicAdd(&posacc[assign[i]], pv[i] * d * inv * 2.0f);   // * (1/TAU)
  }
}

// ---------------- neg = exp(hn@hn^T/TAU) bf16 + f32 rowsum (r7-verified) ----------------
__global__ __launch_bounds__(256) void k_neg_mfma(
    const u16* __restrict__ hnb, u16* __restrict__ negb, float* __restrict__ negsum){
  __shared__ u16 wlds[4][2][2048];
  const int t  = threadIdx.x;
  const int w  = t >> 6;
  const int l  = t & 63;
  const int c  = l & 15;
  const int lg = l >> 4;
  const int j0 = blockIdx.x * 256;
  const int i0 = blockIdx.y * 64;

  const int wrow = l >> 2;
  const int wswz = (l&3) ^ ((wrow>>1)&3);

  #define NSTAGE_W(k0, buf) do { \
    _Pragma("unroll") \
    for (int i_=0;i_<4;i_++){ \
      int row_ = j0 + w*64 + i_*16 + wrow; \
      glds16(hnb + (size_t)row_*HID + (k0) + wswz*8, &wlds[w][buf][i_*512]); \
    } } while(0)

  const u16* irow[4];
#pragma unroll
  for (int mf=0;mf<4;mf++)
    irow[mf] = hnb + (size_t)(i0 + mf*16 + c)*HID + lg*8;

  f32x4 acc[4][4];
#pragma unroll
  for (int i=0;i<4;i++)
#pragma unroll
    for (int j=0;j<4;j++){ acc[i][j].x=0.f; acc[i][j].y=0.f; acc[i][j].z=0.f; acc[i][j].w=0.f; }

  const int su = lg ^ ((c>>1)&3);

  bf16x8 xreg[2][4];
  NSTAGE_W(0, 0);
#pragma unroll
  for (int mf=0;mf<4;mf++) xreg[0][mf] = *reinterpret_cast<const bf16x8*>(irow[mf]);

#pragma unroll
  for (int ks=0; ks<8; ks++){
    const int buf = ks & 1;
    if (ks < 7){
      NSTAGE_W((ks+1)*32, buf^1);
#pragma unroll
      for (int mf=0;mf<4;mf++)
        xreg[buf^1][mf] = *reinterpret_cast<const bf16x8*>(irow[mf] + (ks+1)*32);
      VMWAIT8();
    } else {
      VMWAIT0();
    }
#pragma unroll
    for (int nf=0; nf<4; nf++){
      bf16x8 afr = *reinterpret_cast<const bf16x8*>(&wlds[w][buf][((nf*16+c)*4 + su)*8]);
#pragma unroll
      for (int mf=0; mf<4; mf++)
        acc[mf][nf] = __builtin_amdgcn_mfma_f32_16x16x32_bf16(afr, xreg[buf][mf], acc[mf][nf], 0,0,0);
    }
  }

#pragma unroll
  for (int mf=0; mf<4; mf++){
    int i = i0 + mf*16 + c;
    float rs = 0.f;
#pragma unroll
    for (int nf=0; nf<4; nf++){
      f32x4 a = acc[mf][nf];
      float e0 = __expf(a.x*2.0f), e1 = __expf(a.y*2.0f);
      float e2 = __expf(a.z*2.0f), e3 = __expf(a.w*2.0f);
      rs += e0+e1+e2+e3;
      uint2 p; p.x = pk2(e0, e1); p.y = pk2(e2, e3);
      *reinterpret_cast<uint2*>(negb + (size_t)i*M_CL + j0 + w*64 + nf*16 + lg*4) = p;
    }
    rs += __shfl_xor(rs, 16, 64); rs += __shfl_xor(rs, 32, 64);
    if (lg == 0) atomicAdd(&negsum[i], rs);
  }
  #undef NSTAGE_W
}

// ---------------- loss (+ fused finalize via ticket) ----------------
__global__ __launch_bounds__(256) void k_loss(const u16* __restrict__ negb, const float* __restrict__ negsum,
                                              const float* __restrict__ posacc, const int* __restrict__ start,
                                              const int* __restrict__ scol, const float* __restrict__ sval,
                                              double* __restrict__ lossd, int* __restrict__ done,
                                              float* __restrict__ out){
  const int i = blockIdx.x, t = threadIdx.x;
  float ps[8] = {};
  const int s0 = start[i], s1 = start[i+1];
  for (int e=s0;e<s1;e++){
    int c = scol[e];
    float v = sval[e];
    bf16x8 r = *reinterpret_cast<const bf16x8*>(negb + (size_t)c*M_CL + t*8);
#pragma unroll
    for (int jj=0;jj<8;jj++) ps[jj] = fmaf(v, bf2f((u16)r[jj]), ps[jj]);
  }
  float pos = __expf(posacc[i]);
  f32x4 nsa = *reinterpret_cast<const f32x4*>(negsum + t*8);
  f32x4 nsb = *reinterpret_cast<const f32x4*>(negsum + t*8 + 4);
  float ns[8] = {nsa.x,nsa.y,nsa.z,nsa.w,nsb.x,nsb.y,nsb.z,nsb.w};
  float part = 0.f;
#pragma unroll
  for (int jj=0;jj<8;jj++)
    part += __logf(pos + ns[jj]) - __logf(pos + ps[jj]);  // LAMDA = 1
#pragma unroll
  for (int off=32;off;off>>=1) part += __shfl_xor(part, off, 64);
  __shared__ float wsum[4];
  if ((t&63) == 0) wsum[t>>6] = part;
  __syncthreads();
  if (t == 0){
    double s = (double)wsum[0] + (double)wsum[1] + (double)wsum[2] + (double)wsum[3];
    atomicAdd(lossd, s);
    __threadfence();
    int ticket = atomicAdd(done, 1);
    if (ticket == M_CL - 1){
      __threadfence();
      double tot = atomicAdd(lossd, 0.0);
      out[0] = (float)(tot / ((double)M_CL * (double)M_CL));
    }
  }
}

// ---------------- launch ----------------
extern "C" void kernel_launch(void* const* d_in, const int* in_sizes, int n_in,
                              void* d_out, int out_size, void* d_ws, size_t ws_size,
                              hipStream_t stream){
  const float* x    = (const float*)d_in[0];
  const float* We0  = (const float*)d_in[1];
  const float* be0  = (const float*)d_in[2];
  const float* We1  = (const float*)d_in[3];
  const float* be1  = (const float*)d_in[4];
  const float* Wt0  = (const float*)d_in[5];
  const float* bt0  = (const float*)d_in[6];
  const float* Wt1  = (const float*)d_in[7];
  const float* bt1  = (const float*)d_in[8];
  const float* Wp0  = (const float*)d_in[9];
  const float* bp0  = (const float*)d_in[10];
  const float* Wp1  = (const float*)d_in[11];
  const float* bp1  = (const float*)d_in[12];
  const float* pv   = (const float*)d_in[13];
  const float* cgv  = (const float*)d_in[14];
  const int*   pas  = (const int*)d_in[15];
  const int*   cgr  = (const int*)d_in[16];
  const int*   cgc  = (const int*)d_in[17];

  char* ws = (char*)d_ws;
  float*  posacc  = (float*)(ws + OFF_POSACC);
  float*  negsum  = (float*)(ws + OFF_NEGSUM);
  int*    cur_p   = (int*)  (ws + OFF_CURP);
  int*    cur_e   = (int*)  (ws + OFF_CURE);
  int*    hist_p  = (int*)  (ws + OFF_HISTP);
  int*    hist_e  = (int*)  (ws + OFF_HISTE);
  double* lossd   = (double*)(ws + OFF_LOSS);
  int*    done    = (int*)  (ws + OFF_DONE);
  int*    start_p = (int*)  (ws + OFF_STARTP);
  int*    start_e = (int*)  (ws + OFF_STARTE);
  int*    sortpt  = (int*)  (ws + OFF_SORTPT);
  int*    scol    = (int*)  (ws + OFF_SCOL);
  float*  sval    = (float*)(ws + OFF_SVAL);
  float*  cnt     = (float*)(ws + OFF_CNT);
  float*  Xc      = (float*)(ws + OFF_XC);
  float*  qb      = (float*)(ws + OFF_Q);
  u16*    hnb     = (u16*)  (ws + OFF_HNB);
  u16*    negb    = (u16*)  (ws + OFF_NEGB);
  u16*    Wt0t    = (u16*)  (ws + OFF_WT0T);
  u16*    Wt1t    = (u16*)  (ws + OFF_WT1T);
  u16*    xbf     = (u16*)  (ws + OFF_XBF);
  u16*    tbuf    = (u16*)  (ws + OFF_TBUF);
  float*  pss     = (float*)(ws + OFF_PSS);
  float*  pd      = (float*)(ws + OFF_PD);

  k_pre0<<<(ZERO_U32 + 255)/256, 256, 0, stream>>>((unsigned*)ws);
  k_hist<<<NB_HP + NB_HE, 256, 0, stream>>>(pas, cgr, hist_p, hist_e);
  k_scan2<<<1, 256, 0, stream>>>(hist_p, start_p, hist_e, start_e);
  k_misc<<<NB_P + NB_E + NB_T0 + NB_T1, 256, 0, stream>>>(
      pas, cgr, cgc, cgv, start_p, start_e, cur_p, cur_e,
      sortpt, scol, sval, Wt0, Wt1, Wt0t, Wt1t);

  k_cluster_agg<<<M_CL, 256, 0, stream>>>(x, pv, sortpt, start_p, Xc, cnt, xbf);

  k_mchain<<<M_CL/4, 256, 0, stream>>>(Xc, cnt, We0, be0, We1, be1, Wp0, bp0, Wp1, bp1, hnb, qb);

  dim3 gneg(M_CL/256, M_CL/64);
  k_neg_mfma<<<gneg, 256, 0, stream>>>(hnb, negb, negsum);

  k_t0<<<256, 512, 0, stream>>>(xbf, Wt0t, bt0, tbuf);
  k_t1<<<256, 512, 0, stream>>>(tbuf, Wt1t, bt1, qb, pas, pss, pd);
  k_t2<<<(N_PTS + 255)/256, 256, 0, stream>>>(pss, pd, pas, pv, posacc);

  k_loss<<<M_CL, 256, 0, stream>>>(negb, negsum, posacc, start_e, scol, sval, lossd, done, (float*)d_out);
}

// Round 12
// 357.361 us; speedup vs baseline: 1.5286x; 1.5286x over previous
//
#include <hip/hip_runtime.h>
#include <hip/hip_bf16.h>
#include <math.h>

#define N_PTS  100000
#define M_CL   2048
#define E_EDG  65536
#define IN_DIM 512
#define HID    256
// TAU = 0.5 -> 1/TAU = 2.0 ; LAMDA = 1.0 (folded)

typedef unsigned short u16;
typedef __attribute__((ext_vector_type(8))) short bf16x8;
typedef __attribute__((ext_vector_type(4))) float f32x4;

__device__ __forceinline__ u16 f2bf(float f){
  __hip_bfloat16 h = __float2bfloat16(f);
  return *reinterpret_cast<u16*>(&h);
}
__device__ __forceinline__ unsigned pk2(float a, float b){
  return (unsigned)f2bf(a) | ((unsigned)f2bf(b) << 16);
}
__device__ __forceinline__ float bf2f(u16 v){
  return __uint_as_float((unsigned)v << 16);
}
// async global->LDS, 16B per lane: HW dest = wave-uniform base + lane*16B.
__device__ __forceinline__ void glds16(const u16* g, u16* lds_base_uniform){
  __builtin_amdgcn_global_load_lds(
      (const __attribute__((address_space(1))) unsigned int*)(g),
      (__attribute__((address_space(3))) unsigned int*)(lds_base_uniform), 16, 0, 0);
}
#define VMWAIT0() do{ asm volatile("s_waitcnt vmcnt(0)" ::: "memory"); __builtin_amdgcn_sched_barrier(0);}while(0)
#define VMWAIT4() do{ asm volatile("s_waitcnt vmcnt(4)" ::: "memory"); __builtin_amdgcn_sched_barrier(0);}while(0)
#define VMWAIT8() do{ asm volatile("s_waitcnt vmcnt(8)" ::: "memory"); __builtin_amdgcn_sched_barrier(0);}while(0)

// ---------------- workspace layout (bytes) — r11-verified (no aliases) ----------------
static const size_t OFF_POSACC = 0;              // M floats
static const size_t OFF_NEGSUM = 8192;           // M floats
static const size_t OFF_CURP   = 16384;          // M ints
static const size_t OFF_CURE   = 24576;          // M ints
static const size_t OFF_HISTP  = 32768;          // M ints
static const size_t OFF_HISTE  = 40960;          // M ints
static const size_t OFF_LOSS   = 49152;          // 1 double
static const size_t OFF_DONE   = 49160;          // 1 int
static const int    ZERO_U32   = 12291;          // 49164 / 4
static const size_t OFF_STARTP = 49664;          // M+1 ints (ends 57860)
static const size_t OFF_STARTE = 58368;          // M+1 ints (ends 66564)
static const size_t OFF_SORTPT = 66816;          // N ints   (ends 466816)
static const size_t OFF_SCOL   = 466944;         // E ints
static const size_t OFF_SVAL   = 729088;         // E floats
static const size_t OFF_CNT    = 991232;         // M floats
static const size_t OFF_XC     = 999424;         // M*512 f32
static const size_t OFF_Q      = 5193728;        // M*256 f32
static const size_t OFF_HNB    = 7290880;        // M*256 u16
static const size_t OFF_NEGB   = 8388608;        // M*M u16 = 8 MB
static const size_t OFF_WT0T   = 16777216;       // 256*512 bf16
static const size_t OFF_WT1T   = 17039360;       // 256*256 bf16
static const size_t OFF_XBF    = 33554432;       // N*512 bf16 = 102.4 MB

// ---------------- k_init: zeros + both histograms (block-range branched) ----------------
#define NB_Z  ((ZERO_U32 + 255)/256)   // 49
#define NB_HP ((N_PTS + 255)/256)      // 391
#define NB_HE ((E_EDG + 255)/256)      // 256
__global__ __launch_bounds__(256) void k_init(unsigned* __restrict__ zreg,
                                              const int* __restrict__ pas, const int* __restrict__ cgr,
                                              int* __restrict__ hist_p, int* __restrict__ hist_e){
  const int b = blockIdx.x, t = threadIdx.x;
  if (b < NB_Z){
    int i = b*256 + t;
    if (i < ZERO_U32) zreg[i] = 0u;
  } else if (b < NB_Z + NB_HP){
    int i = (b - NB_Z)*256 + t;
    if (i < N_PTS) atomicAdd(&hist_p[pas[i]], 1);
  } else {
    int e = (b - NB_Z - NB_HP)*256 + t;
    if (e < E_EDG) atomicAdd(&hist_e[cgr[e]], 1);
  }
}

// ---------------- k_scan2: exclusive scans of both histograms (1 block) ----------------
__device__ __forceinline__ void scan8(const int* __restrict__ hist, int* __restrict__ start, int* part){
  const int t = threadIdx.x;
  int v[8]; int s = 0;
#pragma unroll
  for (int j=0;j<8;j++){ v[j] = hist[t*8+j]; s += v[j]; }
  part[t] = s;
  __syncthreads();
  if (t == 0){
    int run = 0;
    for (int i=0;i<256;i++){ int tmp = part[i]; part[i] = run; run += tmp; }
  }
  __syncthreads();
  int run = part[t];
#pragma unroll
  for (int j=0;j<8;j++){ start[t*8+j] = run; run += v[j]; }
  if (t == 255) start[M_CL] = run;
}
__global__ __launch_bounds__(256) void k_scan2(const int* __restrict__ hp, int* __restrict__ sp,
                                               const int* __restrict__ he, int* __restrict__ se){
  __shared__ int part[256];
  scan8(hp, sp, part);
  __syncthreads();
  scan8(he, se, part);
}

// ---------------- k_misc: scatters + weight transposes ----------------
#define NB_P  ((N_PTS + 255)/256)
#define NB_E  ((E_EDG + 255)/256)
#define NB_T0 ((256*512)/256)
#define NB_T1 ((256*256)/256)
__global__ __launch_bounds__(256) void k_misc(
    const int* __restrict__ pas, const int* __restrict__ cgr, const int* __restrict__ cgc,
    const float* __restrict__ cgv, const int* __restrict__ start_p, const int* __restrict__ start_e,
    int* __restrict__ cur_p, int* __restrict__ cur_e,
    int* __restrict__ sortpt, int* __restrict__ scol, float* __restrict__ sval,
    const float* __restrict__ Wt0, const float* __restrict__ Wt1,
    u16* __restrict__ Wt0t, u16* __restrict__ Wt1t){
  const int b = blockIdx.x, t = threadIdx.x;
  if (b < NB_P){
    int i = b*256 + t;
    if (i < N_PTS){
      int r = pas[i];
      int p = start_p[r] + atomicAdd(&cur_p[r], 1);
      sortpt[p] = i;
    }
  } else if (b < NB_P + NB_E){
    int e = (b - NB_P)*256 + t;
    if (e < E_EDG){
      int r = cgr[e];
      int p = start_e[r] + atomicAdd(&cur_e[r], 1);
      scol[p] = cgc[e];
      sval[p] = cgv[e];
    }
  } else if (b < NB_P + NB_E + NB_T0){
    int o = (b - NB_P - NB_E)*256 + t;
    int n = o / IN_DIM, k = o % IN_DIM;
    Wt0t[o] = f2bf(Wt0[(size_t)k*HID + n]);
  } else {
    int o = (b - NB_P - NB_E - NB_T0)*256 + t;
    int n = o / HID, k = o % HID;
    Wt1t[o] = f2bf(Wt1[(size_t)k*HID + n]);
  }
}

// ---------------- Xc = segsum(p*x), cnt = segsum(p), xbf = bf16(x) ----------------
__global__ __launch_bounds__(256) void k_cluster_agg(const float* __restrict__ x, const float* __restrict__ pv,
                                                     const int* __restrict__ sorted_pt, const int* __restrict__ start,
                                                     float* __restrict__ Xc, float* __restrict__ cnt,
                                                     u16* __restrict__ xbf){
  const int m = blockIdx.x;
  const int t = threadIdx.x;
  const int half = t >> 7;
  const int u = t & 127;
  const int s0 = start[m], s1 = start[m+1];
  f32x4 a = {0.f,0.f,0.f,0.f};
  float c = 0.f;
  for (int p = s0 + half; p < s1; p += 2){
    int row = sorted_pt[p];
    float w = pv[row];
    f32x4 xv = *reinterpret_cast<const f32x4*>(x + (size_t)row*IN_DIM + u*4);
    a.x = fmaf(w, xv.x, a.x); a.y = fmaf(w, xv.y, a.y);
    a.z = fmaf(w, xv.z, a.z); a.w = fmaf(w, xv.w, a.w);
    c += w;
    uint2 pk; pk.x = pk2(xv.x, xv.y); pk.y = pk2(xv.z, xv.w);
    *reinterpret_cast<uint2*>(xbf + (size_t)row*IN_DIM + u*4) = pk;
  }
  __shared__ __align__(16) float sh[128*4];
  __shared__ float shc[2];
  if (half == 1) *reinterpret_cast<f32x4*>(sh + u*4) = a;
  if (t == 0)   shc[0] = c;
  if (t == 128) shc[1] = c;
  __syncthreads();
  if (half == 0){
    f32x4 b = *reinterpret_cast<const f32x4*>(sh + u*4);
    a.x += b.x; a.y += b.y; a.z += b.z; a.w += b.w;
    *reinterpret_cast<f32x4*>(Xc + (size_t)m*IN_DIM + u*4) = a;
    if (t == 0) cnt[m] = shc[0] + shc[1];
  }
}

// ---------------- fused M-scale chain ----------------
template<int K>
__device__ __forceinline__ void mc_layer(const float* __restrict__ W, const float* act, int t, float acc[4]){
#pragma unroll
  for (int r=0;r<4;r++) acc[r] = 0.f;
#pragma unroll 2
  for (int k=0;k<K;k+=4){
    float w0 = W[(size_t)(k+0)*HID + t];
    float w1 = W[(size_t)(k+1)*HID + t];
    float w2 = W[(size_t)(k+2)*HID + t];
    float w3 = W[(size_t)(k+3)*HID + t];
#pragma unroll
    for (int r=0;r<4;r++){
      float4 av = *reinterpret_cast<const float4*>(act + r*K + k);
      acc[r] = fmaf(av.x, w0, acc[r]);
      acc[r] = fmaf(av.y, w1, acc[r]);
      acc[r] = fmaf(av.z, w2, acc[r]);
      acc[r] = fmaf(av.w, w3, acc[r]);
    }
  }
}

__global__ __launch_bounds__(256) void k_mchain(
    const float* __restrict__ Xc, const float* __restrict__ cnt,
    const float* __restrict__ We0, const float* __restrict__ be0,
    const float* __restrict__ We1, const float* __restrict__ be1,
    const float* __restrict__ Wp0, const float* __restrict__ bp0,
    const float* __restrict__ Wp1, const float* __restrict__ bp1,
    u16* __restrict__ hnb, float* __restrict__ q){
  __shared__ __align__(16) float a_sh[4*512];
  __shared__ __align__(16) float b_sh[4*256];
  __shared__ float part[4][4];
  const int t = threadIdx.x;
  const int rb = blockIdx.x*4;
  for (int i=t; i<4*128; i+=256){
    int r = i>>7, k4 = i&127;
    reinterpret_cast<float4*>(a_sh + r*512)[k4] =
      reinterpret_cast<const float4*>(Xc + (size_t)(rb+r)*IN_DIM)[k4];
  }
  float cv[4];
#pragma unroll
  for (int r=0;r<4;r++) cv[r] = cnt[rb+r];
  __syncthreads();

  float acc[4], v[4];
  mc_layer<512>(We0, a_sh, t, acc);
  {
    float b = be0[t];
#pragma unroll
    for (int r=0;r<4;r++) b_sh[r*256+t] = fmaf(cv[r], b, acc[r]);
  }
  __syncthreads();
  mc_layer<256>(We1, b_sh, t, acc);
  {
    float b = be1[t];
#pragma unroll
    for (int r=0;r<4;r++){
      v[r] = fmaf(cv[r], b, acc[r]);
      float s = v[r]*v[r];
#pragma unroll
      for (int off=32;off;off>>=1) s += __shfl_xor(s, off, 64);
      if ((t&63) == 0) part[t>>6][r] = s;
      a_sh[r*256+t] = v[r];
    }
  }
  __syncthreads();
#pragma unroll
  for (int r=0;r<4;r++){
    float tot = part[0][r]+part[1][r]+part[2][r]+part[3][r];
    float inv = 1.0f / fmaxf(sqrtf(tot), 1e-12f);
    hnb[(size_t)(rb+r)*HID + t] = f2bf(v[r]*inv);
  }
  mc_layer<256>(Wp0, a_sh, t, acc);
  {
    float b = bp0[t];
#pragma unroll
    for (int r=0;r<4;r++) b_sh[r*256+t] = fmaxf(acc[r]+b, 0.f);
  }
  __syncthreads();
  mc_layer<256>(Wp1, b_sh, t, acc);
  {
    float b = bp1[t];
#pragma unroll
    for (int r=0;r<4;r++){
      v[r] = acc[r] + b;
      float s = v[r]*v[r];
#pragma unroll
      for (int off=32;off;off>>=1) s += __shfl_xor(s, off, 64);
      if ((t&63) == 0) part[t>>6][r] = s;
    }
  }
  __syncthreads();
#pragma unroll
  for (int r=0;r<4;r++){
    float tot = part[0][r]+part[1][r]+part[2][r]+part[3][r];
    float inv = 1.0f / fmaxf(sqrtf(tot), 1e-12f);
    q[(size_t)(rb+r)*HID + t] = v[r]*inv;
  }
}

// ---------------- fused target + neg (r8-verified): blocks [0,256) = neg, rest = target ----------------
#define NEG_BLKS 256
#define TGT_BLKS ((N_PTS + 63)/64)    // 1563
__global__ __launch_bounds__(256,2) void k_tneg(
    const u16* __restrict__ xbf, const u16* __restrict__ Wt0t, const float* __restrict__ bt0,
    const u16* __restrict__ Wt1t, const float* __restrict__ bt1,
    const float* __restrict__ q, const int* __restrict__ assign,
    const float* __restrict__ pv, float* __restrict__ posacc,
    const u16* __restrict__ hnb, u16* __restrict__ negb, float* __restrict__ negsum){
  __shared__ u16 wlds[4][2][2048];
  __shared__ u16 act[16384];
  __shared__ float red[2][4][4][16];

  const int t  = threadIdx.x;
  const int w  = t >> 6;
  const int l  = t & 63;
  const int c  = l & 15;
  const int lg = l >> 4;
  const int wrow = l >> 2;
  const int wswz = (l&3) ^ ((wrow>>1)&3);
  const int su = lg ^ ((c>>1)&3);

  f32x4 acc[4][4];
#pragma unroll
  for (int i=0;i<4;i++)
#pragma unroll
    for (int j=0;j<4;j++){ acc[i][j].x=0.f; acc[i][j].y=0.f; acc[i][j].z=0.f; acc[i][j].w=0.f; }

  if (blockIdx.x < NEG_BLKS){
    const int b  = blockIdx.x;
    const int j0 = (b & 7) * 256;
    const int i0 = (b >> 3) * 64;

    #define NSTAGE_W(k0, buf) do { \
      _Pragma("unroll") \
      for (int i_=0;i_<4;i_++){ \
        int row_ = j0 + w*64 + i_*16 + wrow; \
        glds16(hnb + (size_t)row_*HID + (k0) + wswz*8, &wlds[w][buf][i_*512]); \
      } } while(0)

    const u16* irow[4];
#pragma unroll
    for (int mf=0;mf<4;mf++)
      irow[mf] = hnb + (size_t)(i0 + mf*16 + c)*HID + lg*8;

    bf16x8 xreg[2][4];
    NSTAGE_W(0, 0);
#pragma unroll
    for (int mf=0;mf<4;mf++) xreg[0][mf] = *reinterpret_cast<const bf16x8*>(irow[mf]);

#pragma unroll
    for (int ks=0; ks<8; ks++){
      const int buf = ks & 1;
      if (ks < 7){
        NSTAGE_W((ks+1)*32, buf^1);
#pragma unroll
        for (int mf=0;mf<4;mf++)
          xreg[buf^1][mf] = *reinterpret_cast<const bf16x8*>(irow[mf] + (ks+1)*32);
        VMWAIT8();
      } else {
        VMWAIT0();
      }
#pragma unroll
      for (int nf=0; nf<4; nf++){
        bf16x8 afr = *reinterpret_cast<const bf16x8*>(&wlds[w][buf][((nf*16+c)*4 + su)*8]);
#pragma unroll
        for (int mf=0; mf<4; mf++)
          acc[mf][nf] = __builtin_amdgcn_mfma_f32_16x16x32_bf16(afr, xreg[buf][mf], acc[mf][nf], 0,0,0);
      }
    }

#pragma unroll
    for (int mf=0; mf<4; mf++){
      int i = i0 + mf*16 + c;
      float rs = 0.f;
#pragma unroll
      for (int nf=0; nf<4; nf++){
        f32x4 a = acc[mf][nf];
        float e0 = __expf(a.x*2.0f), e1 = __expf(a.y*2.0f);
        float e2 = __expf(a.z*2.0f), e3 = __expf(a.w*2.0f);
        rs += e0+e1+e2+e3;
        uint2 p; p.x = pk2(e0, e1); p.y = pk2(e2, e3);
        *reinterpret_cast<uint2*>(negb + (size_t)i*M_CL + j0 + w*64 + nf*16 + lg*4) = p;
      }
      rs += __shfl_xor(rs, 16, 64); rs += __shfl_xor(rs, 32, 64);
      if (lg == 0) atomicAdd(&negsum[i], rs);
    }
    #undef NSTAGE_W
    return;
  }

  // ---- target path ----
  const int gm0 = (blockIdx.x - NEG_BLKS) * 64;

  #define TSTAGE_W(Wt, K, k0, buf) do { \
    _Pragma("unroll") \
    for (int i_=0;i_<4;i_++){ \
      int row_ = w*64 + i_*16 + wrow; \
      glds16((Wt) + (size_t)row_*(K) + (k0) + wswz*8, &wlds[w][buf][i_*512]); \
    } } while(0)

  const u16* xrow[4];
#pragma unroll
  for (int mf=0;mf<4;mf++){
    int gm = gm0 + mf*16 + c; if (gm > N_PTS-1) gm = N_PTS-1;
    xrow[mf] = xbf + (size_t)gm*IN_DIM + lg*8;
  }

  bf16x8 xreg[2][4];
  TSTAGE_W(Wt0t, IN_DIM, 0, 0);
#pragma unroll
  for (int mf=0;mf<4;mf++) xreg[0][mf] = *reinterpret_cast<const bf16x8*>(xrow[mf]);

#pragma unroll
  for (int ks=0; ks<16; ks++){
    const int buf = ks & 1;
    if (ks < 15){
      TSTAGE_W(Wt0t, IN_DIM, (ks+1)*32, buf^1);
#pragma unroll
      for (int mf=0;mf<4;mf++)
        xreg[buf^1][mf] = *reinterpret_cast<const bf16x8*>(xrow[mf] + (ks+1)*32);
      VMWAIT8();
    } else {
      VMWAIT0();
    }
#pragma unroll
    for (int nf=0; nf<4; nf++){
      bf16x8 afr = *reinterpret_cast<const bf16x8*>(&wlds[w][buf][((nf*16+c)*4 + su)*8]);
#pragma unroll
      for (int mf=0; mf<4; mf++)
        acc[mf][nf] = __builtin_amdgcn_mfma_f32_16x16x32_bf16(afr, xreg[buf][mf], acc[mf][nf], 0,0,0);
    }
  }

#pragma unroll
  for (int nf=0; nf<4; nf++){
    f32x4 bias = *reinterpret_cast<const f32x4*>(bt0 + w*64 + nf*16 + lg*4);
#pragma unroll
    for (int mf=0; mf<4; mf++){
      int m = mf*16 + c;
      f32x4 v = acc[mf][nf] + bias;
      uint2 p; p.x = pk2(v.x, v.y); p.y = pk2(v.z, v.w);
      int u = (w*8 + nf*2 + (lg>>1)) ^ (c&7);
      *reinterpret_cast<uint2*>(act + (m*32 + u)*8 + (lg&1)*4) = p;
    }
  }
#pragma unroll
  for (int i=0;i<4;i++)
#pragma unroll
    for (int j=0;j<4;j++){ acc[i][j].x=0.f; acc[i][j].y=0.f; acc[i][j].z=0.f; acc[i][j].w=0.f; }
  __syncthreads();

  TSTAGE_W(Wt1t, HID, 0, 0);
#pragma unroll
  for (int ks=0; ks<8; ks++){
    const int buf = ks & 1;
    if (ks < 7){
      TSTAGE_W(Wt1t, HID, (ks+1)*32, buf^1);
      VMWAIT4();
    } else {
      VMWAIT0();
    }
    bf16x8 bfr[4];
#pragma unroll
    for (int mf=0; mf<4; mf++){
      int m = mf*16 + c;
      int u = (ks*4 + lg) ^ (c&7);
      bfr[mf] = *reinterpret_cast<const bf16x8*>(act + (m*32 + u)*8);
    }
#pragma unroll
    for (int nf=0; nf<4; nf++){
      bf16x8 afr = *reinterpret_cast<const bf16x8*>(&wlds[w][buf][((nf*16+c)*4 + su)*8]);
#pragma unroll
      for (int mf=0; mf<4; mf++)
        acc[mf][nf] = __builtin_amdgcn_mfma_f32_16x16x32_bf16(afr, bfr[mf], acc[mf][nf], 0,0,0);
    }
  }

#pragma unroll
  for (int mf=0; mf<4; mf++){
    int gm = gm0 + mf*16 + c;
    int cl = assign[(gm < N_PTS) ? gm : (N_PTS-1)];
    const float* qrow = q + (size_t)cl*HID + w*64 + lg*4;
    float ss = 0.f, d = 0.f;
#pragma unroll
    for (int nf=0; nf<4; nf++){
      f32x4 b  = *reinterpret_cast<const f32x4*>(bt1 + w*64 + nf*16 + lg*4);
      f32x4 qv = *reinterpret_cast<const f32x4*>(qrow + nf*16);
      f32x4 v  = acc[mf][nf] + b;
      ss = fmaf(v.x,v.x, fmaf(v.y,v.y, fmaf(v.z,v.z, fmaf(v.w,v.w, ss))));
      d  = fmaf(v.x,qv.x, fmaf(v.y,qv.y, fmaf(v.z,qv.z, fmaf(v.w,qv.w, d))));
    }
    ss += __shfl_xor(ss, 16, 64); ss += __shfl_xor(ss, 32, 64);
    d  += __shfl_xor(d , 16, 64); d  += __shfl_xor(d , 32, 64);
    if (lg == 0){ red[0][w][mf][c] = ss; red[1][w][mf][c] = d; }
  }
  __syncthreads();
  if (t < 64){
    int gm = gm0 + t;
    if (gm < N_PTS){
      int mf = t>>4, cc = t&15;
      float ss = red[0][0][mf][cc]+red[0][1][mf][cc]+red[0][2][mf][cc]+red[0][3][mf][cc];
      float d  = red[1][0][mf][cc]+red[1][1][mf][cc]+red[1][2][mf][cc]+red[1][3][mf][cc];
      float inv = 1.0f / fmaxf(sqrtf(ss), 1e-12f);
      atomicAdd(&posacc[assign[gm]], pv[gm] * d * inv * 2.0f);   // * (1/TAU)
    }
  }
  #undef TSTAGE_W
}

// ---------------- loss (+ fused finalize via ticket) ----------------
__global__ __launch_bounds__(256) void k_loss(const u16* __restrict__ negb, const float* __restrict__ negsum,
                                              const float* __restrict__ posacc, const int* __restrict__ start,
                                              const int* __restrict__ scol, const float* __restrict__ sval,
                                              double* __restrict__ lossd, int* __restrict__ done,
                                              float* __restrict__ out){
  const int i = blockIdx.x, t = threadIdx.x;
  float ps[8] = {};
  const int s0 = start[i], s1 = start[i+1];
  for (int e=s0;e<s1;e++){
    int c = scol[e];
    float v = sval[e];
    bf16x8 r = *reinterpret_cast<const bf16x8*>(negb + (size_t)c*M_CL + t*8);
#pragma unroll
    for (int jj=0;jj<8;jj++) ps[jj] = fmaf(v, bf2f((u16)r[jj]), ps[jj]);
  }
  float pos = __expf(posacc[i]);
  f32x4 nsa = *reinterpret_cast<const f32x4*>(negsum + t*8);
  f32x4 nsb = *reinterpret_cast<const f32x4*>(negsum + t*8 + 4);
  float ns[8] = {nsa.x,nsa.y,nsa.z,nsa.w,nsb.x,nsb.y,nsb.z,nsb.w};
  float part = 0.f;
#pragma unroll
  for (int jj=0;jj<8;jj++)
    part += __logf(pos + ns[jj]) - __logf(pos + ps[jj]);  // LAMDA = 1
#pragma unroll
  for (int off=32;off;off>>=1) part += __shfl_xor(part, off, 64);
  __shared__ float wsum[4];
  if ((t&63) == 0) wsum[t>>6] = part;
  __syncthreads();
  if (t == 0){
    double s = (double)wsum[0] + (double)wsum[1] + (double)wsum[2] + (double)wsum[3];
    atomicAdd(lossd, s);
    __threadfence();
    int ticket = atomicAdd(done, 1);
    if (ticket == M_CL - 1){
      __threadfence();
      double tot = atomicAdd(lossd, 0.0);
      out[0] = (float)(tot / ((double)M_CL * (double)M_CL));
    }
  }
}

// ---------------- launch ----------------
extern "C" void kernel_launch(void* const* d_in, const int* in_sizes, int n_in,
                              void* d_out, int out_size, void* d_ws, size_t ws_size,
                              hipStream_t stream){
  const float* x    = (const float*)d_in[0];
  const float* We0  = (const float*)d_in[1];
  const float* be0  = (const float*)d_in[2];
  const float* We1  = (const float*)d_in[3];
  const float* be1  = (const float*)d_in[4];
  const float* Wt0  = (const float*)d_in[5];
  const float* bt0  = (const float*)d_in[6];
  const float* Wt1  = (const float*)d_in[7];
  const float* bt1  = (const float*)d_in[8];
  const float* Wp0  = (const float*)d_in[9];
  const float* bp0  = (const float*)d_in[10];
  const float* Wp1  = (const float*)d_in[11];
  const float* bp1  = (const float*)d_in[12];
  const float* pv   = (const float*)d_in[13];
  const float* cgv  = (const float*)d_in[14];
  const int*   pas  = (const int*)d_in[15];
  const int*   cgr  = (const int*)d_in[16];
  const int*   cgc  = (const int*)d_in[17];

  char* ws = (char*)d_ws;
  float*  posacc  = (float*)(ws + OFF_POSACC);
  float*  negsum  = (float*)(ws + OFF_NEGSUM);
  int*    cur_p   = (int*)  (ws + OFF_CURP);
  int*    cur_e   = (int*)  (ws + OFF_CURE);
  int*    hist_p  = (int*)  (ws + OFF_HISTP);
  int*    hist_e  = (int*)  (ws + OFF_HISTE);
  double* lossd   = (double*)(ws + OFF_LOSS);
  int*    done    = (int*)  (ws + OFF_DONE);
  int*    start_p = (int*)  (ws + OFF_STARTP);
  int*    start_e = (int*)  (ws + OFF_STARTE);
  int*    sortpt  = (int*)  (ws + OFF_SORTPT);
  int*    scol    = (int*)  (ws + OFF_SCOL);
  float*  sval    = (float*)(ws + OFF_SVAL);
  float*  cnt     = (float*)(ws + OFF_CNT);
  float*  Xc      = (float*)(ws + OFF_XC);
  float*  qb      = (float*)(ws + OFF_Q);
  u16*    hnb     = (u16*)  (ws + OFF_HNB);
  u16*    negb    = (u16*)  (ws + OFF_NEGB);
  u16*    Wt0t    = (u16*)  (ws + OFF_WT0T);
  u16*    Wt1t    = (u16*)  (ws + OFF_WT1T);
  u16*    xbf     = (u16*)  (ws + OFF_XBF);

  k_init<<<NB_Z + NB_HP + NB_HE, 256, 0, stream>>>((unsigned*)ws, pas, cgr, hist_p, hist_e);
  k_scan2<<<1, 256, 0, stream>>>(hist_p, start_p, hist_e, start_e);
  k_misc<<<NB_P + NB_E + NB_T0 + NB_T1, 256, 0, stream>>>(
      pas, cgr, cgc, cgv, start_p, start_e, cur_p, cur_e,
      sortpt, scol, sval, Wt0, Wt1, Wt0t, Wt1t);

  k_cluster_agg<<<M_CL, 256, 0, stream>>>(x, pv, sortpt, start_p, Xc, cnt, xbf);

  k_mchain<<<M_CL/4, 256, 0, stream>>>(Xc, cnt, We0, be0, We1, be1, Wp0, bp0, Wp1, bp1, hnb, qb);

  k_tneg<<<NEG_BLKS + TGT_BLKS, 256, 0, stream>>>(
      xbf, Wt0t, bt0, Wt1t, bt1, qb, pas, pv, posacc, hnb, negb, negsum);

  k_loss<<<M_CL, 256, 0, stream>>>(negb, negsum, posacc, start_e, scol, sval, lossd, done, (float*)d_out);
}